// Round 3
// baseline (181.581 us; speedup 1.0000x reference)
//
#include <hip/hip_runtime.h>
#include <hip/hip_cooperative_groups.h>

namespace cg = cooperative_groups;

// GCN B=2, N=8192, F=64, O=64 — fp32. adj[b,i,j] = si_i + sj_j + c is
// rank-structured, so the whole layer collapses to O(B*N*F):
//   deg_i = N*(si_i + c) + SjT_b,  d = rsqrt(max(deg,1))
//   out[i,o] = relu( d_i*((si_i+c)*U[o] + V[o]) + bias_o )
//   U = (Σ_j d_j x_j) @ W,   V = (Σ_j sj_j d_j x_j) @ W
// Single cooperative kernel: x read from HBM exactly once (LDS tile reused
// across phases), no atomics, no workspace zeroing (write-before-read).

#define NN 8192
#define FF 64

__global__ __launch_bounds__(256) void gcn_fused(
    const float* __restrict__ x,      // (2,8192,64)
    const float* __restrict__ adj_w,  // (128,)
    const float* __restrict__ adj_b,  // (1,)
    const float* __restrict__ weight, // (64,64)
    const float* __restrict__ bias,   // (64,)
    float* __restrict__ out,          // (2,8192,64)
    float* __restrict__ parts1,       // 256 floats
    float* __restrict__ parts2p,      // 256*64 floats
    float* __restrict__ parts2q)      // 256*64 floats
{
    __shared__ float xs[64 * FF];       // 16 KB block x-tile
    __shared__ float sis[64], sjs[64];
    __shared__ float wjs[FF], wis[FF];
    __shared__ float red[256];          // multi-use scratch (parts1 stage, then d per row)
    __shared__ float p2[256], q2[256];
    __shared__ float ps[FF], qs[FF];
    __shared__ float Us[FF], Vs[FF];
    __shared__ float SjTs;

    cg::grid_group grid = cg::this_grid();

    const int tid = threadIdx.x;
    const int blk = blockIdx.x;          // 0..255
    const int batch = blk >> 7;          // 128 blocks per batch
    const int rowbase = blk * 64;        // global row 0..16383

    if (tid < 2 * FF) {
        float v = adj_w[tid];
        if (tid < FF) wjs[tid] = v; else wis[tid - FF] = v;
    }
    __syncthreads();

    const int q4 = tid & 15;             // float4 slot within a row
    const int rl = tid >> 4;             // 0..15
    const float4 wjv = reinterpret_cast<const float4*>(wjs)[q4];
    const float4 wiv = reinterpret_cast<const float4*>(wis)[q4];

    // ---- Phase 1: stage 64 rows into LDS, per-row si/sj ----
    #pragma unroll
    for (int pass = 0; pass < 4; ++pass) {
        int r = pass * 16 + rl;
        int row = rowbase + r;
        float4 xv = reinterpret_cast<const float4*>(x + (size_t)row * FF)[q4];
        reinterpret_cast<float4*>(xs + r * FF)[q4] = xv;
        float a = xv.x * wjv.x + xv.y * wjv.y + xv.z * wjv.z + xv.w * wjv.w;
        float b = xv.x * wiv.x + xv.y * wiv.y + xv.z * wiv.z + xv.w * wiv.w;
        #pragma unroll
        for (int s = 8; s; s >>= 1) {
            a += __shfl_down(a, s, 16);
            b += __shfl_down(b, s, 16);
        }
        if (q4 == 0) { sjs[r] = a; sis[r] = b; }
    }
    __syncthreads();
    if (tid < 64) {                       // block-partial sum of sj (wave 0)
        float a = sjs[tid];
        #pragma unroll
        for (int s = 32; s; s >>= 1) a += __shfl_down(a, s, 64);
        if (tid == 0) parts1[blk] = a;
    }
    __threadfence();
    grid.sync();

    // ---- Phase 2: SjT, per-row d, block-partial p/q from LDS tile ----
    if (tid < 128) red[tid] = parts1[batch * 128 + tid];
    __syncthreads();
    if (tid < 64) {
        float a = red[tid] + red[tid + 64];
        #pragma unroll
        for (int s = 32; s; s >>= 1) a += __shfl_down(a, s, 64);
        if (tid == 0) SjTs = a;
    }
    __syncthreads();
    const float cadj = adj_b[0];
    const float sjt = SjTs;
    if (tid < 64) {
        float siv = sis[tid];
        float deg = 8192.f * (siv + cadj) + sjt;
        red[tid] = rsqrtf(fmaxf(deg, 1.f));   // d per local row
    }
    __syncthreads();

    const int f = tid & 63, g = tid >> 6;     // g uniform within each wave
    {
        float pa = 0.f, qa = 0.f;
        for (int r = g; r < 64; r += 4) {
            float d = red[r];
            float sd = sjs[r] * d;
            float xv = xs[r * FF + f];
            pa += d * xv;
            qa += sd * xv;
        }
        p2[tid] = pa; q2[tid] = qa;
    }
    __syncthreads();
    if (tid < 64) {
        parts2p[blk * 64 + tid] = p2[tid] + p2[tid + 64] + p2[tid + 128] + p2[tid + 192];
        parts2q[blk * 64 + tid] = q2[tid] + q2[tid + 64] + q2[tid + 128] + q2[tid + 192];
    }
    __threadfence();
    grid.sync();

    // ---- Phase 3: batch-wide p,q then U,V (redundant per block, L2-hot) ----
    {
        float pa = 0.f, qa = 0.f;
        for (int b2 = g; b2 < 128; b2 += 4) {
            size_t idx = (size_t)(batch * 128 + b2) * 64 + f;
            pa += parts2p[idx];
            qa += parts2q[idx];
        }
        p2[tid] = pa; q2[tid] = qa;
    }
    __syncthreads();
    if (tid < 64) {
        ps[tid] = p2[tid] + p2[tid + 64] + p2[tid + 128] + p2[tid + 192];
        qs[tid] = q2[tid] + q2[tid + 64] + q2[tid + 128] + q2[tid + 192];
    }
    __syncthreads();
    if (tid < 128) {
        int sel = tid >> 6, o = tid & 63;
        const float* src = sel ? qs : ps;
        float s = 0.f;
        #pragma unroll
        for (int k = 0; k < FF; ++k) s += src[k] * weight[k * 64 + o];
        (sel ? Vs : Us)[o] = s;
    }
    __syncthreads();

    // ---- Phase 4: epilogue, float4 stores ----
    const float4 bv = reinterpret_cast<const float4*>(bias)[q4];
    const float4 Uv = reinterpret_cast<const float4*>(Us)[q4];
    const float4 Vv = reinterpret_cast<const float4*>(Vs)[q4];
    #pragma unroll
    for (int pass = 0; pass < 4; ++pass) {
        int r = pass * 16 + rl;
        int row = rowbase + r;
        float siv = sis[r];
        float deg = 8192.f * (siv + cadj) + sjt;
        float d = rsqrtf(fmaxf(deg, 1.f));
        float a = d * (siv + cadj);
        float4 o;
        o.x = fmaxf(a * Uv.x + d * Vv.x + bv.x, 0.f);
        o.y = fmaxf(a * Uv.y + d * Vv.y + bv.y, 0.f);
        o.z = fmaxf(a * Uv.z + d * Vv.z + bv.z, 0.f);
        o.w = fmaxf(a * Uv.w + d * Vv.w + bv.w, 0.f);
        reinterpret_cast<float4*>(out + (size_t)row * FF)[q4] = o;
    }
}

extern "C" void kernel_launch(void* const* d_in, const int* in_sizes, int n_in,
                              void* d_out, int out_size, void* d_ws, size_t ws_size,
                              hipStream_t stream) {
    const float* x      = (const float*)d_in[0];
    const float* adj_w  = (const float*)d_in[1];
    const float* adj_b  = (const float*)d_in[2];
    const float* weight = (const float*)d_in[3];
    const float* bias   = (const float*)d_in[4];
    float* out = (float*)d_out;

    float* parts1  = (float*)d_ws;          // 256 floats
    float* parts2p = parts1 + 256;          // 16384 floats
    float* parts2q = parts2p + 16384;       // 16384 floats
    // all workspace is written before read — no zeroing dispatch needed

    void* args[] = { (void*)&x, (void*)&adj_w, (void*)&adj_b, (void*)&weight,
                     (void*)&bias, (void*)&out, (void*)&parts1,
                     (void*)&parts2p, (void*)&parts2q };
    hipLaunchCooperativeKernel((const void*)gcn_fused, dim3(256), dim3(256),
                               args, 0, stream);
}

// Round 4
// 82.676 us; speedup vs baseline: 2.1963x; 2.1963x over previous
//
#include <hip/hip_runtime.h>

// GCN B=2, N=8192, F=64, O=64 — fp32. adj[b,i,j] = si_i + sj_j + c is
// rank-structured => layer collapses to O(B*N*F):
//   deg_i = N*(si_i + c) + SjT_b,  d_i = rsqrt(max(deg_i,1))
//   out[i,o] = relu( d_i*((si_i+c)*U[o] + V[o]) + bias_o )
//   U = (Σ_j d_j x_j) @ W,   V = (Σ_j sj_j d_j x_j) @ W
// 3 stream-ordered kernels (kernel boundary = the global sync; cooperative
// grid.sync() measured ~50µs/sync on this grid — R2 post-mortem).
// No atomics, no workspace zeroing: all ws is write-before-read.

#define NN 8192
#define FF 64

// K1: 256 blocks x 256 thr, 64 rows/block. Per-row si/sj + block-partial Σsj.
__global__ __launch_bounds__(256) void k1_sisj(const float* __restrict__ x,
                                               const float* __restrict__ adj_w,
                                               float* __restrict__ si,
                                               float* __restrict__ sj,
                                               float* __restrict__ parts1) {
    __shared__ float wjs[FF], wis[FF], sjs[64];
    int tid = threadIdx.x;
    if (tid < 2 * FF) {
        float v = adj_w[tid];
        if (tid < FF) wjs[tid] = v; else wis[tid - FF] = v;
    }
    __syncthreads();
    int q4 = tid & 15, rl = tid >> 4;
    float4 wjv = reinterpret_cast<const float4*>(wjs)[q4];
    float4 wiv = reinterpret_cast<const float4*>(wis)[q4];
    int rowbase = blockIdx.x * 64;
    #pragma unroll
    for (int pass = 0; pass < 4; ++pass) {
        int r = pass * 16 + rl;
        int row = rowbase + r;
        float4 xv = reinterpret_cast<const float4*>(x + (size_t)row * FF)[q4];
        float a = xv.x * wjv.x + xv.y * wjv.y + xv.z * wjv.z + xv.w * wjv.w;
        float b = xv.x * wiv.x + xv.y * wiv.y + xv.z * wiv.z + xv.w * wiv.w;
        #pragma unroll
        for (int s = 8; s; s >>= 1) {
            a += __shfl_down(a, s, 16);
            b += __shfl_down(b, s, 16);
        }
        if (q4 == 0) { sj[row] = a; si[row] = b; sjs[r] = a; }
    }
    __syncthreads();
    if (tid < 64) {
        float a = sjs[tid];
        #pragma unroll
        for (int s = 32; s; s >>= 1) a += __shfl_down(a, s, 64);
        if (tid == 0) parts1[blockIdx.x] = a;   // 128 per batch
    }
}

// K2: 128 blocks x 256 thr, 128 rows/block. SjT (redundant), d per row
// (stored for K3), block-partial p/q.
__global__ __launch_bounds__(256) void k2_pq(const float* __restrict__ x,
                                             const float* __restrict__ adj_b,
                                             const float* __restrict__ si,
                                             const float* __restrict__ sj,
                                             const float* __restrict__ parts1,
                                             float* __restrict__ dglob,
                                             float* __restrict__ p2,
                                             float* __restrict__ q2) {
    __shared__ float red[128], dsh[128], sjdsh[128];
    __shared__ float pacc[256], qacc[256];
    __shared__ float SjTs;
    int tid = threadIdx.x;
    int batch = blockIdx.x >> 6;                 // 64 blocks/batch
    int base = batch * NN + (blockIdx.x & 63) * 128;
    if (tid < 128) red[tid] = parts1[batch * 128 + tid];
    __syncthreads();
    if (tid < 64) {
        float a = red[tid] + red[tid + 64];
        #pragma unroll
        for (int s = 32; s; s >>= 1) a += __shfl_down(a, s, 64);
        if (tid == 0) SjTs = a;
    }
    __syncthreads();
    float cadj = adj_b[0];
    if (tid < 128) {
        int row = base + tid;
        float siv = si[row], sjv = sj[row];
        float d = rsqrtf(fmaxf(8192.f * (siv + cadj) + SjTs, 1.f));
        dsh[tid] = d; sjdsh[tid] = sjv * d;
        dglob[row] = d;
    }
    __syncthreads();
    int f = tid & 63, g = tid >> 6;
    float pa = 0.f, qa = 0.f;
    for (int r = g; r < 128; r += 4) {
        float xv = x[(size_t)(base + r) * FF + f];
        pa += dsh[r] * xv;
        qa += sjdsh[r] * xv;
    }
    pacc[tid] = pa; qacc[tid] = qa;
    __syncthreads();
    if (tid < 64) {
        p2[blockIdx.x * 64 + tid] = pacc[tid] + pacc[tid + 64] + pacc[tid + 128] + pacc[tid + 192];
        q2[blockIdx.x * 64 + tid] = qacc[tid] + qacc[tid + 64] + qacc[tid + 128] + qacc[tid + 192];
    }
}

// K3: 256 blocks x 256 thr, 64 rows/block. Reduce parts2 (redundant, L2-hot),
// U/V matvec, epilogue with float4 stores.
__global__ __launch_bounds__(256) void k3_out(const float* __restrict__ adj_b,
                                              const float* __restrict__ weight,
                                              const float* __restrict__ bias,
                                              const float* __restrict__ si,
                                              const float* __restrict__ dglob,
                                              const float* __restrict__ p2,
                                              const float* __restrict__ q2,
                                              float* __restrict__ out) {
    __shared__ float pacc[256], qacc[256];
    __shared__ float ps[64], qs[64], Us[64], Vs[64];
    __shared__ float dr[64], sir[64];
    int tid = threadIdx.x;
    int batch = blockIdx.x >> 7;                 // 128 blocks/batch
    int rowbase = blockIdx.x * 64;
    if (tid < 64) { dr[tid] = dglob[rowbase + tid]; sir[tid] = si[rowbase + tid]; }
    int f = tid & 63, g = tid >> 6;
    float pa = 0.f, qa = 0.f;
    for (int b2 = g; b2 < 64; b2 += 4) {         // 64 K2-blocks per batch
        size_t idx = (size_t)(batch * 64 + b2) * 64 + f;
        pa += p2[idx];
        qa += q2[idx];
    }
    pacc[tid] = pa; qacc[tid] = qa;
    __syncthreads();
    if (tid < 64) {
        ps[tid] = pacc[tid] + pacc[tid + 64] + pacc[tid + 128] + pacc[tid + 192];
        qs[tid] = qacc[tid] + qacc[tid + 64] + qacc[tid + 128] + qacc[tid + 192];
    }
    __syncthreads();
    if (tid < 128) {
        int sel = tid >> 6, o = tid & 63;
        const float* src = sel ? qs : ps;
        float s = 0.f;
        #pragma unroll
        for (int k = 0; k < FF; ++k) s += src[k] * weight[k * 64 + o];
        (sel ? Vs : Us)[o] = s;
    }
    __syncthreads();
    float cadj = adj_b[0];
    int q4 = tid & 15, rl = tid >> 4;
    float4 bv = reinterpret_cast<const float4*>(bias)[q4];
    float4 Uv = reinterpret_cast<const float4*>(Us)[q4];
    float4 Vv = reinterpret_cast<const float4*>(Vs)[q4];
    #pragma unroll
    for (int pass = 0; pass < 4; ++pass) {
        int r = pass * 16 + rl;
        int row = rowbase + r;
        float d = dr[r];
        float a = d * (sir[r] + cadj);
        float4 o;
        o.x = fmaxf(a * Uv.x + d * Vv.x + bv.x, 0.f);
        o.y = fmaxf(a * Uv.y + d * Vv.y + bv.y, 0.f);
        o.z = fmaxf(a * Uv.z + d * Vv.z + bv.z, 0.f);
        o.w = fmaxf(a * Uv.w + d * Vv.w + bv.w, 0.f);
        reinterpret_cast<float4*>(out + (size_t)row * FF)[q4] = o;
    }
}

extern "C" void kernel_launch(void* const* d_in, const int* in_sizes, int n_in,
                              void* d_out, int out_size, void* d_ws, size_t ws_size,
                              hipStream_t stream) {
    const float* x      = (const float*)d_in[0];   // (2,8192,64)
    const float* adj_w  = (const float*)d_in[1];   // (128,)
    const float* adj_b  = (const float*)d_in[2];   // (1,)
    const float* weight = (const float*)d_in[3];   // (64,64)
    const float* bias   = (const float*)d_in[4];   // (64,)
    float* out = (float*)d_out;                    // (2,8192,64)

    float* ws     = (float*)d_ws;
    float* si     = ws;                 // 16384
    float* sj     = ws + 16384;         // 16384
    float* dglob  = ws + 32768;         // 16384
    float* parts1 = ws + 49152;         // 256
    float* p2     = ws + 49408;         // 8192
    float* q2     = ws + 57600;         // 8192  (end 65792 floats = 263 KB)

    k1_sisj<<<256, 256, 0, stream>>>(x, adj_w, si, sj, parts1);
    k2_pq  <<<128, 256, 0, stream>>>(x, adj_b, si, sj, parts1, dglob, p2, q2);
    k3_out <<<256, 256, 0, stream>>>(adj_b, weight, bias, si, dglob, p2, q2, out);
}